// Round 1
// baseline (20889.517 us; speedup 1.0000x reference)
//
#include <hip/hip_runtime.h>
#include <stdint.h>

// LSTM speed benchmark: 2-layer LSTMCell H=2048, T=2048, future=128.
// Strategy: register-resident recurrent GEMVs + epoch-tagged cross-chip h exchange.
// Workspace layout (needs ~97 MB):
//   h1ex  [2][2048] u64   @ 0        (value|epoch packed exchange)
//   h2ex  [2][2048] u64   @ 32768
//   H1    [2048][2048] f32 @ 65536            (h1 history)
//   H2    [2048][2048] f32 @ 65536+16M        (h2 history)
//   IG2   [2048][8192] f32 @ 65536+32M        (w_ih2 @ h1(t), batched)
//   c1f   [2048] f32       @ 65536+96M
//   c2f   [2048] f32       @ 65536+96M+8192

typedef unsigned long long u64;
typedef unsigned int u32;

#define HD 2048
#define TT 2048
#define FUT 128
#define G4 8192

__device__ __forceinline__ float sigm_(float x) {
    return 1.0f / (1.0f + __expf(-x));
}
__device__ __forceinline__ float tanh_(float x) {
    float xc = fminf(fmaxf(x, -15.0f), 15.0f);
    float e = __expf(2.0f * xc);
    return 1.0f - 2.0f / (e + 1.0f);
}

// Poll two epoch-tagged slots until tag matches; bounded to avoid hangs.
__device__ __forceinline__ void poll2(u64* p0, u64* p1, u32 tag,
                                      float* o0, float* o1, int* alive) {
    u64 v0 = 0, v1 = 0;
    int d0 = 0, d1 = 0, guard = 0;
    while (*alive) {
        if (!d0) { v0 = __hip_atomic_load(p0, __ATOMIC_RELAXED, __HIP_MEMORY_SCOPE_AGENT); d0 = ((u32)(v0 >> 32) == tag); }
        if (!d1) { v1 = __hip_atomic_load(p1, __ATOMIC_RELAXED, __HIP_MEMORY_SCOPE_AGENT); d1 = ((u32)(v1 >> 32) == tag); }
        if (d0 & d1) break;
        __builtin_amdgcn_s_sleep(2);
        if (++guard > (1 << 21)) *alive = 0;   // fail visibly, never hang
    }
    *o0 = __uint_as_float((u32)v0);
    *o1 = __uint_as_float((u32)v1);
}

__device__ __forceinline__ void publish1(u64* p, float v, u32 tag) {
    u64 pk = ((u64)tag << 32) | (u64)__float_as_uint(v);
    __hip_atomic_store(p, pk, __ATOMIC_RELAXED, __HIP_MEMORY_SCOPE_AGENT);
}

// ---------------------------------------------------------------------------
// Phase A / C: one-layer recurrence with register-resident weights.
// 256 blocks x 1024 threads, 1 block/CU. Block b owns h outputs j=b*8..b*8+7
// (32 gate rows). Thread (chunk=tid>>5, br=tid&31) holds 64 weights of
// row(br) at cols chunk*64..chunk*64+63.
// addin: layer1 -> b_ih1+b_hh1 + w_ih1[row]*x(t);  layer2 -> b's + IG2[t][row].
// ---------------------------------------------------------------------------
__global__ void __launch_bounds__(1024, 4)
recur_kernel(const float* __restrict__ Wrec,
             const float* __restrict__ aiv,     // w_ih1 or nullptr
             const float* __restrict__ ba,
             const float* __restrict__ bb,
             const float* __restrict__ xseq,    // input or nullptr
             const float* __restrict__ ig2,     // nullptr or [TT][G4]
             u64* __restrict__ hex,
             float* __restrict__ hist,
             float* __restrict__ cfin)
{
    __shared__ float lds_h[HD];
    __shared__ float lds_p[32][33];
    __shared__ float lds_g[32];
    __shared__ float lds_x[TT];

    const int tid = threadIdx.x;
    const int br = tid & 31;
    const int chunk = tid >> 5;
    const int gate = br >> 3;
    const int jj = br & 7;
    const int row = gate * HD + blockIdx.x * 8 + jj;
    const int e0 = tid * 2, e1 = tid * 2 + 1;

    // one-time resident weight load (64 fp32 / thread)
    float w[64];
    {
        const float* src = Wrec + (size_t)row * HD + chunk * 64;
        #pragma unroll
        for (int q = 0; q < 64; q += 4) {
            float4 v = *reinterpret_cast<const float4*>(src + q);
            w[q] = v.x; w[q + 1] = v.y; w[q + 2] = v.z; w[q + 3] = v.w;
        }
    }
    const float myb = ba[row] + bb[row];
    const float myaiv = aiv ? aiv[row] : 0.0f;

    if (xseq) { lds_x[e0] = xseq[e0]; lds_x[e1] = xseq[e1]; }

    float c = 0.0f;        // cell state: wave0 lanes 0..7
    int alive = 1;

    #pragma unroll 1
    for (int t = 0; t < TT; ++t) {
        // stage h(t-1)
        if (t == 0) {
            lds_h[e0] = 0.0f; lds_h[e1] = 0.0f;
        } else {
            u64* src = hex + (size_t)((t - 1) & 1) * HD;
            poll2(src + e0, src + e1, (u32)t, &lds_h[e0], &lds_h[e1], &alive);
        }
        __syncthreads();

        // prefetch add-in for reducer lanes (hidden under FMA)
        float addv = 0.0f;
        if (tid < 32) addv = ig2 ? ig2[(size_t)t * G4 + row] : myaiv * lds_x[t];

        // partial dot (h broadcast per half-wave from LDS)
        const float* hc = lds_h + chunk * 64;
        float a0 = 0, a1 = 0, a2 = 0, a3 = 0;
        #pragma unroll
        for (int q = 0; q < 64; q += 4) {
            a0 = fmaf(w[q + 0], hc[q + 0], a0);
            a1 = fmaf(w[q + 1], hc[q + 1], a1);
            a2 = fmaf(w[q + 2], hc[q + 2], a2);
            a3 = fmaf(w[q + 3], hc[q + 3], a3);
        }
        lds_p[chunk][br] = (a0 + a1) + (a2 + a3);
        __syncthreads();

        if (tid < 32) {   // wave0: reduce 32 chunks, activate, cell update, publish
            float s0 = 0, s1 = 0, s2 = 0, s3 = 0;
            #pragma unroll
            for (int cc = 0; cc < 32; cc += 4) {
                s0 += lds_p[cc + 0][br];
                s1 += lds_p[cc + 1][br];
                s2 += lds_p[cc + 2][br];
                s3 += lds_p[cc + 3][br];
            }
            float gsum = (s0 + s1) + (s2 + s3) + myb + addv;
            lds_g[br] = (gate == 2) ? tanh_(gsum) : sigm_(gsum);
            // same wave: ds_write by lanes 0..31 precedes reads below in order
            if (br < 8) {
                float gi = lds_g[br], gf = lds_g[8 + br];
                float gg = lds_g[16 + br], go = lds_g[24 + br];
                c = gf * c + gi * gg;
                float h = go * tanh_(c);
                hist[(size_t)t * HD + blockIdx.x * 8 + br] = h;
                publish1(hex + (size_t)(t & 1) * HD + blockIdx.x * 8 + br, h, (u32)(t + 1));
            }
        }
    }
    if (tid < 8) cfin[blockIdx.x * 8 + tid] = c;
}

// ---------------------------------------------------------------------------
// Phase B: IG2[t][r] = sum_k H1[t][k] * W_ih2[r][k]   (fp32, 128x128 tile)
// grid (64, 16), 256 threads, 8x8 per thread.
// ---------------------------------------------------------------------------
__global__ void __launch_bounds__(256)
ig2_gemm_kernel(const float* __restrict__ H1h, const float* __restrict__ W,
                float* __restrict__ IG2)
{
    __shared__ float As[16][132];
    __shared__ float Bs[16][132];
    const int tid = threadIdx.x;
    const int tx = tid & 15;
    const int ty = tid >> 4;
    const int r0 = blockIdx.x * 128;
    const int t0 = blockIdx.y * 128;
    const int stt = tid & 127;
    const int skc = tid >> 7;

    float acc[8][8];
    #pragma unroll
    for (int i = 0; i < 8; ++i)
        #pragma unroll
        for (int j = 0; j < 8; ++j) acc[i][j] = 0.0f;

    #pragma unroll 1
    for (int k0 = 0; k0 < HD; k0 += 16) {
        const float* pa = H1h + (size_t)(t0 + stt) * HD + k0 + skc * 8;
        const float* pb = W   + (size_t)(r0 + stt) * HD + k0 + skc * 8;
        float4 va0 = *reinterpret_cast<const float4*>(pa);
        float4 va1 = *reinterpret_cast<const float4*>(pa + 4);
        float4 vb0 = *reinterpret_cast<const float4*>(pb);
        float4 vb1 = *reinterpret_cast<const float4*>(pb + 4);
        __syncthreads();   // protect LDS vs previous iteration readers
        const int kb = skc * 8;
        As[kb + 0][stt] = va0.x; As[kb + 1][stt] = va0.y; As[kb + 2][stt] = va0.z; As[kb + 3][stt] = va0.w;
        As[kb + 4][stt] = va1.x; As[kb + 5][stt] = va1.y; As[kb + 6][stt] = va1.z; As[kb + 7][stt] = va1.w;
        Bs[kb + 0][stt] = vb0.x; Bs[kb + 1][stt] = vb0.y; Bs[kb + 2][stt] = vb0.z; Bs[kb + 3][stt] = vb0.w;
        Bs[kb + 4][stt] = vb1.x; Bs[kb + 5][stt] = vb1.y; Bs[kb + 6][stt] = vb1.z; Bs[kb + 7][stt] = vb1.w;
        __syncthreads();
        #pragma unroll
        for (int kk = 0; kk < 16; ++kk) {
            float4 fa0 = *reinterpret_cast<const float4*>(&As[kk][ty * 8]);
            float4 fa1 = *reinterpret_cast<const float4*>(&As[kk][ty * 8 + 4]);
            float4 fb0 = *reinterpret_cast<const float4*>(&Bs[kk][tx * 8]);
            float4 fb1 = *reinterpret_cast<const float4*>(&Bs[kk][tx * 8 + 4]);
            float av[8] = {fa0.x, fa0.y, fa0.z, fa0.w, fa1.x, fa1.y, fa1.z, fa1.w};
            float bv[8] = {fb0.x, fb0.y, fb0.z, fb0.w, fb1.x, fb1.y, fb1.z, fb1.w};
            #pragma unroll
            for (int i = 0; i < 8; ++i)
                #pragma unroll
                for (int j = 0; j < 8; ++j)
                    acc[i][j] = fmaf(av[i], bv[j], acc[i][j]);
        }
    }
    #pragma unroll
    for (int i = 0; i < 8; ++i) {
        float* pc = IG2 + (size_t)(t0 + ty * 8 + i) * G4 + (r0 + tx * 8);
        *reinterpret_cast<float4*>(pc)     = make_float4(acc[i][0], acc[i][1], acc[i][2], acc[i][3]);
        *reinterpret_cast<float4*>(pc + 4) = make_float4(acc[i][4], acc[i][5], acc[i][6], acc[i][7]);
    }
}

// ---------------------------------------------------------------------------
// Phase E: out[t] = b_lin + sum_k H2[t][k]*w_lin[k],  t in [0,2048)
// ---------------------------------------------------------------------------
__global__ void __launch_bounds__(256)
outs_kernel(const float* __restrict__ H2h, const float* __restrict__ wl,
            const float* __restrict__ bl, float* __restrict__ out)
{
    const int t = blockIdx.x;
    const int tid = threadIdx.x;
    const float* h = H2h + (size_t)t * HD + tid * 8;
    const float* wp = wl + tid * 8;
    float4 h0 = *reinterpret_cast<const float4*>(h);
    float4 h1 = *reinterpret_cast<const float4*>(h + 4);
    float4 w0 = *reinterpret_cast<const float4*>(wp);
    float4 w1 = *reinterpret_cast<const float4*>(wp + 4);
    float s = h0.x * w0.x;
    s = fmaf(h0.y, w0.y, s); s = fmaf(h0.z, w0.z, s); s = fmaf(h0.w, w0.w, s);
    s = fmaf(h1.x, w1.x, s); s = fmaf(h1.y, w1.y, s);
    s = fmaf(h1.z, w1.z, s); s = fmaf(h1.w, w1.w, s);
    #pragma unroll
    for (int off = 32; off > 0; off >>= 1) s += __shfl_down(s, off, 64);
    __shared__ float red[4];
    if ((tid & 63) == 0) red[tid >> 6] = s;
    __syncthreads();
    if (tid == 0) out[t] = red[0] + red[1] + red[2] + red[3] + bl[0];
}

// ---------------------------------------------------------------------------
// Phase D: 128 coupled future steps; weights streamed from L3.
// Same 256x1024 cooperative shape; out(t) computed redundantly per block.
// ---------------------------------------------------------------------------
__global__ void __launch_bounds__(1024, 4)
future_kernel(const float* __restrict__ Whh1, const float* __restrict__ Wih2,
              const float* __restrict__ Whh2,
              const float* __restrict__ wih1,
              const float* __restrict__ bih1, const float* __restrict__ bhh1,
              const float* __restrict__ bih2, const float* __restrict__ bhh2,
              const float* __restrict__ wl, const float* __restrict__ bl,
              u64* __restrict__ h1ex, u64* __restrict__ h2ex,
              const float* __restrict__ c1f, const float* __restrict__ c2f,
              float* __restrict__ out)
{
    __shared__ float lds_h1[HD];
    __shared__ float lds_h2[HD];
    __shared__ float lds_wl[HD];
    __shared__ float lds_p[32][33];
    __shared__ float lds_g[32];
    __shared__ float lds_red[17];

    const int tid = threadIdx.x;
    const int rl = tid >> 5;       // row_local for streamed GEMV
    const int kl = tid & 31;
    const int gate = rl >> 3, jj = rl & 7;
    const int row = gate * HD + blockIdx.x * 8 + jj;
    const int e0 = tid * 2, e1 = tid * 2 + 1;
    const int wid = tid >> 6;
    const int lane = tid & 63;

    // reducer-lane constants (reducer lane i handles row_local = i)
    float rb1 = 0, rb2 = 0, raiv = 0;
    if (tid < 32) {
        int rg = tid >> 3, rj = tid & 7;
        int rr = rg * HD + blockIdx.x * 8 + rj;
        rb1 = bih1[rr] + bhh1[rr];
        rb2 = bih2[rr] + bhh2[rr];
        raiv = wih1[rr];
    }
    const float blin = bl[0];
    lds_wl[e0] = wl[e0]; lds_wl[e1] = wl[e1];

    float c1 = 0.0f, c2 = 0.0f;
    if (tid < 8) {
        c1 = c1f[blockIdx.x * 8 + tid];
        c2 = c2f[blockIdx.x * 8 + tid];
    }
    int alive = 1;

    // prologue: stage h1(2047) from phase A (slot 1, tag 2048)
    poll2(h1ex + HD + e0, h1ex + HD + e1, (u32)TT, &lds_h1[e0], &lds_h1[e1], &alive);

    #pragma unroll 1
    for (int t = TT; t < TT + FUT; ++t) {
        // stage h2(t-1): slot (t-1)&1, tag t
        {
            u64* src = h2ex + (size_t)((t - 1) & 1) * HD;
            poll2(src + e0, src + e1, (u32)t, &lds_h2[e0], &lds_h2[e1], &alive);
        }
        __syncthreads();

        // out(t-1) = w_lin . h2(t-1) + b_lin  (redundant, bitwise-identical per block)
        float s = fmaf(lds_wl[e0], lds_h2[e0], lds_wl[e1] * lds_h2[e1]);
        #pragma unroll
        for (int off = 32; off > 0; off >>= 1) s += __shfl_down(s, off, 64);
        if (lane == 0) lds_red[wid] = s;
        __syncthreads();
        float xcur;
        {
            float ss = 0;
            #pragma unroll
            for (int i2 = 0; i2 < 16; ++i2) ss += lds_red[i2];
            xcur = ss + blin;
        }
        if (t > TT && tid == 0 && blockIdx.x == 0) out[t - 1] = xcur;

        // GEMV1: gates1 = Whh1 @ h1(t-1)   (streamed from L3)
        {
            const float* wr = Whh1 + (size_t)row * HD + kl * 4;
            const float* hb = lds_h1 + kl * 4;
            float a0 = 0, a1 = 0, a2 = 0, a3 = 0;
            #pragma unroll
            for (int q = 0; q < 16; ++q) {
                float4 wv = *reinterpret_cast<const float4*>(wr + q * 128);
                float4 hv = *reinterpret_cast<const float4*>(hb + q * 128);
                a0 = fmaf(wv.x, hv.x, a0); a1 = fmaf(wv.y, hv.y, a1);
                a2 = fmaf(wv.z, hv.z, a2); a3 = fmaf(wv.w, hv.w, a3);
            }
            lds_p[rl][kl] = (a0 + a1) + (a2 + a3);
        }
        __syncthreads();
        if (tid < 32) {
            float s0 = 0, s1 = 0, s2 = 0, s3 = 0;
            #pragma unroll
            for (int cc = 0; cc < 32; cc += 4) {
                s0 += lds_p[tid][cc + 0]; s1 += lds_p[tid][cc + 1];
                s2 += lds_p[tid][cc + 2]; s3 += lds_p[tid][cc + 3];
            }
            float g1 = (s0 + s1) + (s2 + s3) + rb1 + raiv * xcur;
            lds_g[tid] = ((tid >> 3) == 2) ? tanh_(g1) : sigm_(g1);
            if (tid < 8) {
                float gi = lds_g[tid], gf = lds_g[8 + tid];
                float gg = lds_g[16 + tid], go = lds_g[24 + tid];
                c1 = gf * c1 + gi * gg;
                float h = go * tanh_(c1);
                publish1(h1ex + (size_t)(t & 1) * HD + blockIdx.x * 8 + tid, h, (u32)(t + 1));
            }
        }
        // stage h1(t) (everyone, incl. publishers)
        {
            u64* src = h1ex + (size_t)(t & 1) * HD;
            poll2(src + e0, src + e1, (u32)(t + 1), &lds_h1[e0], &lds_h1[e1], &alive);
        }
        __syncthreads();

        // GEMV2: gates2 = Wih2 @ h1(t) + Whh2 @ h2(t-1)   (streamed)
        {
            const float* wr1 = Wih2 + (size_t)row * HD + kl * 4;
            const float* wr2 = Whh2 + (size_t)row * HD + kl * 4;
            const float* hb1 = lds_h1 + kl * 4;
            const float* hb2 = lds_h2 + kl * 4;
            float a0 = 0, a1 = 0, a2 = 0, a3 = 0;
            #pragma unroll
            for (int q = 0; q < 16; ++q) {
                float4 wv = *reinterpret_cast<const float4*>(wr1 + q * 128);
                float4 hv = *reinterpret_cast<const float4*>(hb1 + q * 128);
                a0 = fmaf(wv.x, hv.x, a0); a1 = fmaf(wv.y, hv.y, a1);
                a2 = fmaf(wv.z, hv.z, a2); a3 = fmaf(wv.w, hv.w, a3);
            }
            #pragma unroll
            for (int q = 0; q < 16; ++q) {
                float4 wv = *reinterpret_cast<const float4*>(wr2 + q * 128);
                float4 hv = *reinterpret_cast<const float4*>(hb2 + q * 128);
                a0 = fmaf(wv.x, hv.x, a0); a1 = fmaf(wv.y, hv.y, a1);
                a2 = fmaf(wv.z, hv.z, a2); a3 = fmaf(wv.w, hv.w, a3);
            }
            lds_p[rl][kl] = (a0 + a1) + (a2 + a3);
        }
        __syncthreads();
        if (tid < 32) {
            float s0 = 0, s1 = 0, s2 = 0, s3 = 0;
            #pragma unroll
            for (int cc = 0; cc < 32; cc += 4) {
                s0 += lds_p[tid][cc + 0]; s1 += lds_p[tid][cc + 1];
                s2 += lds_p[tid][cc + 2]; s3 += lds_p[tid][cc + 3];
            }
            float g2 = (s0 + s1) + (s2 + s3) + rb2;
            lds_g[tid] = ((tid >> 3) == 2) ? tanh_(g2) : sigm_(g2);
            if (tid < 8) {
                float gi = lds_g[tid], gf = lds_g[8 + tid];
                float gg = lds_g[16 + tid], go = lds_g[24 + tid];
                c2 = gf * c2 + gi * gg;
                float h = go * tanh_(c2);
                publish1(h2ex + (size_t)(t & 1) * HD + blockIdx.x * 8 + tid, h, (u32)(t + 1));
            }
        }
    }

    // epilogue: out(2175) from h2(2175) (slot (2175)&1 = 1, tag 2176)
    {
        u64* src = h2ex + (size_t)((TT + FUT - 1) & 1) * HD;
        poll2(src + e0, src + e1, (u32)(TT + FUT), &lds_h2[e0], &lds_h2[e1], &alive);
    }
    __syncthreads();
    float s = fmaf(lds_wl[e0], lds_h2[e0], lds_wl[e1] * lds_h2[e1]);
    #pragma unroll
    for (int off = 32; off > 0; off >>= 1) s += __shfl_down(s, off, 64);
    if (lane == 0) lds_red[wid] = s;
    __syncthreads();
    if (tid == 0 && blockIdx.x == 0) {
        float ss = 0;
        #pragma unroll
        for (int i2 = 0; i2 < 16; ++i2) ss += lds_red[i2];
        out[TT + FUT - 1] = ss + blin;
    }
}

// ---------------------------------------------------------------------------

extern "C" void kernel_launch(void* const* d_in, const int* in_sizes, int n_in,
                              void* d_out, int out_size, void* d_ws, size_t ws_size,
                              hipStream_t stream) {
    const float* input = (const float*)d_in[0];
    const float* w_ih1 = (const float*)d_in[1];
    const float* w_hh1 = (const float*)d_in[2];
    const float* b_ih1 = (const float*)d_in[3];
    const float* b_hh1 = (const float*)d_in[4];
    const float* w_ih2 = (const float*)d_in[5];
    const float* w_hh2 = (const float*)d_in[6];
    const float* b_ih2 = (const float*)d_in[7];
    const float* b_hh2 = (const float*)d_in[8];
    const float* w_lin = (const float*)d_in[9];
    const float* b_lin = (const float*)d_in[10];
    float* out = (float*)d_out;

    char* ws = (char*)d_ws;
    u64*   h1ex = (u64*)(ws);
    u64*   h2ex = (u64*)(ws + 32768);
    float* H1   = (float*)(ws + 65536);
    float* H2   = (float*)(ws + 65536 + (size_t)16 * 1024 * 1024);
    float* IG2  = (float*)(ws + 65536 + (size_t)32 * 1024 * 1024);
    float* c1f  = (float*)(ws + 65536 + (size_t)96 * 1024 * 1024);
    float* c2f  = (float*)(ws + 65536 + (size_t)96 * 1024 * 1024 + 8192);

    // ---- Phase A: layer-1 recurrence (cooperative) ----
    {
        const float* Wrec = w_hh1; const float* aiv = w_ih1;
        const float* ba = b_ih1;   const float* bb = b_hh1;
        const float* xs = input;   const float* ig = nullptr;
        u64* hx = h1ex; float* hh = H1; float* cf = c1f;
        void* args[] = {&Wrec, &aiv, &ba, &bb, &xs, &ig, &hx, &hh, &cf};
        if (hipLaunchCooperativeKernel((const void*)recur_kernel, dim3(256), dim3(1024),
                                       args, 0, stream) != hipSuccess) {
            (void)hipGetLastError();
            hipLaunchKernelGGL(recur_kernel, dim3(256), dim3(1024), 0, stream,
                               Wrec, aiv, ba, bb, xs, ig, hx, hh, cf);
        }
    }

    // ---- Phase B: IG2 = W_ih2 @ H1^T ----
    hipLaunchKernelGGL(ig2_gemm_kernel, dim3(G4 / 128, TT / 128), dim3(256), 0, stream,
                       H1, w_ih2, IG2);

    // ---- Phase C: layer-2 recurrence (cooperative) ----
    {
        const float* Wrec = w_hh2; const float* aiv = nullptr;
        const float* ba = b_ih2;   const float* bb = b_hh2;
        const float* xs = nullptr; const float* ig = IG2;
        u64* hx = h2ex; float* hh = H2; float* cf = c2f;
        void* args[] = {&Wrec, &aiv, &ba, &bb, &xs, &ig, &hx, &hh, &cf};
        if (hipLaunchCooperativeKernel((const void*)recur_kernel, dim3(256), dim3(1024),
                                       args, 0, stream) != hipSuccess) {
            (void)hipGetLastError();
            hipLaunchKernelGGL(recur_kernel, dim3(256), dim3(1024), 0, stream,
                               Wrec, aiv, ba, bb, xs, ig, hx, hh, cf);
        }
    }

    // ---- Phase E: out[0..2047] ----
    hipLaunchKernelGGL(outs_kernel, dim3(TT), dim3(256), 0, stream, H2, w_lin, b_lin, out);

    // ---- Phase D: 128 future steps (cooperative) ----
    {
        const float* a0 = w_hh1; const float* a1 = w_ih2; const float* a2 = w_hh2;
        const float* a3 = w_ih1;
        const float* a4 = b_ih1; const float* a5 = b_hh1;
        const float* a6 = b_ih2; const float* a7 = b_hh2;
        const float* a8 = w_lin; const float* a9 = b_lin;
        u64* a10 = h1ex; u64* a11 = h2ex;
        const float* a12 = c1f; const float* a13 = c2f;
        float* a14 = out;
        void* args[] = {&a0, &a1, &a2, &a3, &a4, &a5, &a6, &a7, &a8, &a9,
                        &a10, &a11, &a12, &a13, &a14};
        if (hipLaunchCooperativeKernel((const void*)future_kernel, dim3(256), dim3(1024),
                                       args, 0, stream) != hipSuccess) {
            (void)hipGetLastError();
            hipLaunchKernelGGL(future_kernel, dim3(256), dim3(1024), 0, stream,
                               a0, a1, a2, a3, a4, a5, a6, a7, a8, a9,
                               a10, a11, a12, a13, a14);
        }
    }
}